// Round 4
// baseline (176.068 us; speedup 1.0000x reference)
//
#include <hip/hip_runtime.h>

// Problem constants
#define BB 8
#define QQ 128
#define KK 1024
#define DD 256
#define HH 256

// A·V split-K config
#define KSPLIT 8
#define KCH (KK / KSPLIT)   // 128
#define QT 8                // q rows per av block

#define TWO_LOG2E     2.8853900817779268f
#define NEG_TWO_LOG2E -2.8853900817779268f

// ---------------------------------------------------------------------------
// K1: fused Q+K projection with exp2 epilogue.
//   eproj[r][h] = exp2( TWO_LOG2E * sum_d A[r][d] * W[h][d] )
// Block tile 64 rows x 128 h, 256 threads, thread = 4 rows x 8 h.
// ds_read ratio: 12 b128 per 128 MACs (rho=0.094) vs 0.125 before.
// Grid 144x2 = 288 blocks.
// ---------------------------------------------------------------------------
__global__ __launch_bounds__(256) void proj_kernel(const float* __restrict__ queries,
                                                   const float* __restrict__ keys,
                                                   const float* __restrict__ Wq,
                                                   const float* __restrict__ Wk,
                                                   float* __restrict__ eproj) {
    __shared__ float As[64][68];    // +4 pad: <=2-way banks (free)
    __shared__ float Ws[128][68];
    const int t  = threadIdx.x;
    const int tr = t & 15;          // rows {tr+16i, i<4}
    const int th = t >> 4;          // hs   {th+16j, j<8}
    const int r0 = blockIdx.x * 64;
    const int h0 = blockIdx.y * 128;
    const bool isQ = (r0 < BB * QQ);
    const float* A = isQ ? (queries + (size_t)r0 * DD)
                         : (keys + (size_t)(r0 - BB * QQ) * DD);
    const float* W = isQ ? Wq : Wk;

    float acc[4][8] = {};

    for (int dc = 0; dc < DD; dc += 64) {
#pragma unroll
        for (int i = 0; i < 4; ++i) {        // A: 1024 float4 slots
            int fi = t + 256 * i; int row = fi >> 4; int c4 = (fi & 15) << 2;
            *(float4*)&As[row][c4] = *(const float4*)&A[(size_t)row * DD + dc + c4];
        }
#pragma unroll
        for (int i = 0; i < 8; ++i) {        // W: 2048 float4 slots
            int fi = t + 256 * i; int row = fi >> 4; int c4 = (fi & 15) << 2;
            *(float4*)&Ws[row][c4] = *(const float4*)&W[(size_t)(h0 + row) * DD + dc + c4];
        }
        __syncthreads();
#pragma unroll 2
        for (int dd = 0; dd < 64; dd += 4) {
            float4 a4[4], w4[8];
#pragma unroll
            for (int i = 0; i < 4; ++i) a4[i] = *(float4*)&As[tr + 16 * i][dd];
#pragma unroll
            for (int j = 0; j < 8; ++j) w4[j] = *(float4*)&Ws[th + 16 * j][dd];
#pragma unroll
            for (int ri = 0; ri < 4; ++ri)
#pragma unroll
                for (int hi = 0; hi < 8; ++hi) {
                    acc[ri][hi] += a4[ri].x * w4[hi].x + a4[ri].y * w4[hi].y +
                                   a4[ri].z * w4[hi].z + a4[ri].w * w4[hi].w;
                }
        }
        __syncthreads();
    }
#pragma unroll
    for (int ri = 0; ri < 4; ++ri)
#pragma unroll
        for (int hi = 0; hi < 8; ++hi) {
            eproj[(size_t)(r0 + tr + 16 * ri) * HH + h0 + th + 16 * hi] =
                __builtin_amdgcn_exp2f(TWO_LOG2E * acc[ri][hi]);
        }
}

// ---------------------------------------------------------------------------
// K2: unnormalized masked attention weights.
//   acc = sum_h w_v[h] * rcp(eq[b,q,h]*ek[b,k,h] + 1)     (2 full + 1 trans)
//   p = (k < vl) ? exp2(-2log2e * acc) : 0 ;  vl==0 -> p=1 (uniform, ref behavior)
// Block tile 32q x 64k, thread = 2q x 4k. Double-buffered LDS h-chunks with
// register prefetch: 1 barrier per chunk, global latency hidden under trans.
// Grid 16x4x8 = 512 blocks = 2/CU (52 KB LDS/block).
// ---------------------------------------------------------------------------
__global__ __launch_bounds__(256) void score_kernel(const float* __restrict__ eproj,
                                                    const float* __restrict__ wv,
                                                    const int* __restrict__ vlen,
                                                    float* __restrict__ p) {
    __shared__ float qs[2][32][68];
    __shared__ float ks_[2][64][68];
    __shared__ float ws[2][64];
    const int t  = threadIdx.x;
    const int tk = t & 15;   // k's = {tk+16j, j<4}
    const int tq = t >> 4;   // q's = {tq, tq+16}
    const int b  = blockIdx.z;
    const int q0 = blockIdx.y * 32;
    const int k0 = blockIdx.x * 64;

    const float* qpB = eproj + ((size_t)(b * QQ + q0)) * HH;
    const float* kpB = eproj + ((size_t)(BB * QQ + b * KK + k0)) * HH;

    // stage h-chunk 0
#pragma unroll
    for (int i = 0; i < 2; ++i) {
        int fi = t + 256 * i; int row = fi >> 4; int c4 = (fi & 15) << 2;
        *(float4*)&qs[0][row][c4] = *(const float4*)&qpB[(size_t)row * HH + c4];
    }
#pragma unroll
    for (int i = 0; i < 4; ++i) {
        int fi = t + 256 * i; int row = fi >> 4; int c4 = (fi & 15) << 2;
        *(float4*)&ks_[0][row][c4] = *(const float4*)&kpB[(size_t)row * HH + c4];
    }
    if (t < 16) *(float4*)&ws[0][t * 4] = *(const float4*)&wv[t * 4];
    __syncthreads();

    float acc[2][4] = {};

    for (int c = 0; c < 4; ++c) {
        const int cur = c & 1, nxt = cur ^ 1;

        // prefetch next chunk into registers (latency overlaps compute below)
        float4 pq[2], pk[4], pw;
        if (c < 3) {
            const int hc = (c + 1) * 64;
#pragma unroll
            for (int i = 0; i < 2; ++i) {
                int fi = t + 256 * i; int row = fi >> 4; int c4 = (fi & 15) << 2;
                pq[i] = *(const float4*)&qpB[(size_t)row * HH + hc + c4];
            }
#pragma unroll
            for (int i = 0; i < 4; ++i) {
                int fi = t + 256 * i; int row = fi >> 4; int c4 = (fi & 15) << 2;
                pk[i] = *(const float4*)&kpB[(size_t)row * HH + hc + c4];
            }
            if (t < 16) pw = *(const float4*)&wv[hc + t * 4];
        }

        // compute on current chunk (trans-pipe-bound: 32 rcp per 7 ds_read)
#pragma unroll 2
        for (int hh = 0; hh < 64; hh += 4) {
            float4 w4 = *(float4*)&ws[cur][hh];
            const float* wa = (const float*)&w4;
            float4 q4[2], k4[4];
            q4[0] = *(float4*)&qs[cur][tq][hh];
            q4[1] = *(float4*)&qs[cur][tq + 16][hh];
#pragma unroll
            for (int j = 0; j < 4; ++j) k4[j] = *(float4*)&ks_[cur][tk + 16 * j][hh];
#pragma unroll
            for (int i = 0; i < 2; ++i) {
                const float* qa = (const float*)&q4[i];
#pragma unroll
                for (int j = 0; j < 4; ++j) {
                    const float* ka = (const float*)&k4[j];
#pragma unroll
                    for (int cc = 0; cc < 4; ++cc) {
                        float d = __builtin_fmaf(qa[cc], ka[cc], 1.0f);
                        acc[i][j] += wa[cc] * __builtin_amdgcn_rcpf(d);
                    }
                }
            }
        }

        // write prefetched regs into the other buffer; single barrier
        if (c < 3) {
#pragma unroll
            for (int i = 0; i < 2; ++i) {
                int fi = t + 256 * i; int row = fi >> 4; int c4 = (fi & 15) << 2;
                *(float4*)&qs[nxt][row][c4] = pq[i];
            }
#pragma unroll
            for (int i = 0; i < 4; ++i) {
                int fi = t + 256 * i; int row = fi >> 4; int c4 = (fi & 15) << 2;
                *(float4*)&ks_[nxt][row][c4] = pk[i];
            }
            if (t < 16) *(float4*)&ws[nxt][t * 4] = pw;
            __syncthreads();
        }
    }

    const int vl = vlen[b];
#pragma unroll
    for (int i = 0; i < 2; ++i)
#pragma unroll
        for (int j = 0; j < 4; ++j) {
            int q = q0 + tq + 16 * i;
            int k = k0 + tk + 16 * j;
            float pv;
            if (vl == 0) pv = 1.0f;   // all-masked row -> uniform attn (ref behavior)
            else pv = (k < vl) ? __builtin_amdgcn_exp2f(NEG_TWO_LOG2E * acc[i][j])
                               : 0.0f;
            p[((size_t)b * QQ + q) * KK + k] = pv;
        }
}

// ---------------------------------------------------------------------------
// K3: split-K partial A·V on unnormalized p, plus per-chunk row sums.
// Block = (ks, q-tile of 8, b); thread t owns d-column t. 8-deep V prefetch.
// ---------------------------------------------------------------------------
__global__ __launch_bounds__(256) void av_partial(const float* __restrict__ p,
                                                  const float* __restrict__ V,
                                                  float* __restrict__ partial,
                                                  float* __restrict__ psum) {
    __shared__ float a_s[QT][KCH];     // [8][128]
    const int t   = threadIdx.x;       // d index 0..255
    const int ksb = blockIdx.x;        // k-chunk
    const int q0  = blockIdx.y * QT;
    const int b   = blockIdx.z;
    const int kc0 = ksb * KCH;

    const float* pB = p + ((size_t)b * QQ + q0) * KK + kc0;
    const float* VB = V + ((size_t)b * KK + kc0) * DD;

    {   // stage p chunk: 1024 floats = 256 float4, conflict-free
        int qi = t >> 5;
        int k4 = (t & 31) << 2;
        *(float4*)&a_s[qi][k4] = *(const float4*)&pB[(size_t)qi * KK + k4];
    }
    __syncthreads();

    // per-(b,q) chunk sum of p (for softmax denominator)
    if (t < QT) {
        float s = 0.f;
        for (int x = 0; x < KCH; x += 4) {
            float4 v = *(float4*)&a_s[t][x];
            s += v.x + v.y + v.z + v.w;
        }
        psum[((size_t)ksb * BB + b) * QQ + q0 + t] = s;
    }

    float acc[QT] = {};
    float vc[8], vn[8];
#pragma unroll
    for (int j = 0; j < 8; ++j) vc[j] = VB[(size_t)j * DD + t];

    for (int kg = 0; kg < KCH; kg += 8) {
        if (kg + 8 < KCH) {
#pragma unroll
            for (int j = 0; j < 8; ++j) vn[j] = VB[(size_t)(kg + 8 + j) * DD + t];
        }
#pragma unroll
        for (int qi = 0; qi < QT; ++qi) {
            float4 a0 = *(float4*)&a_s[qi][kg];       // broadcast reads (bank-cheap)
            float4 a1 = *(float4*)&a_s[qi][kg + 4];
            acc[qi] += a0.x * vc[0] + a0.y * vc[1] + a0.z * vc[2] + a0.w * vc[3] +
                       a1.x * vc[4] + a1.y * vc[5] + a1.z * vc[6] + a1.w * vc[7];
        }
#pragma unroll
        for (int j = 0; j < 8; ++j) vc[j] = vn[j];
    }

#pragma unroll
    for (int qi = 0; qi < QT; ++qi) {
        partial[(size_t)ksb * (BB * QQ * DD) +
                ((size_t)b * QQ + q0 + qi) * DD + t] = acc[qi];
    }
}

// ---------------------------------------------------------------------------
// K4: reduce partials and normalize by the row sum S. float4 per thread.
// ---------------------------------------------------------------------------
__global__ __launch_bounds__(256) void av_reduce(const float* __restrict__ partial,
                                                 const float* __restrict__ psum,
                                                 float* __restrict__ out) {
    const int i  = blockIdx.x * 256 + threadIdx.x;   // float4 index, 65536 total
    const int bq = i >> 6;                           // / (DD/4)

    float S = 0.f;
#pragma unroll
    for (int ks = 0; ks < KSPLIT; ++ks) S += psum[(size_t)ks * (BB * QQ) + bq];

    const float4* p4 = (const float4*)partial;
    const int stride4 = BB * QQ * DD / 4;            // 65536
    float4 s = p4[i];
#pragma unroll
    for (int ks = 1; ks < KSPLIT; ++ks) {
        float4 x = p4[(size_t)ks * stride4 + i];
        s.x += x.x; s.y += x.y; s.z += x.z; s.w += x.w;
    }
    const float inv = 1.0f / S;   // S>0 always: p>=8e-12 unmasked, vl==0 -> p=1
    s.x *= inv; s.y *= inv; s.z *= inv; s.w *= inv;
    ((float4*)out)[i] = s;
}

// ---------------------------------------------------------------------------
extern "C" void kernel_launch(void* const* d_in, const int* in_sizes, int n_in,
                              void* d_out, int out_size, void* d_ws, size_t ws_size,
                              hipStream_t stream) {
    const float* queries = (const float*)d_in[0];   // [B,Q,D]
    const float* keys    = (const float*)d_in[1];   // [B,K,D]
    const float* values  = (const float*)d_in[2];   // [B,K,D]
    const float* W_q     = (const float*)d_in[3];   // [H,D]
    const float* W_k     = (const float*)d_in[4];   // [H,D]
    const float* w_v     = (const float*)d_in[5];   // [H]
    const int*   vlen    = (const int*)d_in[6];     // [B]
    float* out = (float*)d_out;

    float* ws    = (float*)d_ws;
    float* eproj = ws;                                      // (B*Q + B*K)*H = 2359296
    float* p     = ws + (size_t)(BB * QQ + BB * KK) * HH;   // B*Q*K = 1048576
    float* psum  = p + (size_t)BB * QQ * KK;                // KSPLIT*B*Q = 8192
    // partial aliases eproj (dead after score_kernel): KSPLIT*B*Q*D = 2097152 fits
    float* partial = ws;

    // Fused Q+K projection with exp2 epilogue (64r x 128h tiles)
    proj_kernel<<<dim3((BB * QQ + BB * KK) / 64, HH / 128, 1), 256, 0, stream>>>(
        queries, keys, W_q, W_k, eproj);

    // Unnormalized masked attention weights (double-buffered, 1 trans/term)
    score_kernel<<<dim3(KK / 64, QQ / 32, BB), 256, 0, stream>>>(eproj, w_v, vlen, p);

    // p @ V split-K + chunk row sums
    av_partial<<<dim3(KSPLIT, QQ / QT, BB), 256, 0, stream>>>(p, values, partial, psum);

    // Reduce + softmax normalization
    av_reduce<<<dim3(BB * QQ * DD / 4 / 256, 1, 1), 256, 0, stream>>>(partial, psum, out);
}

// Round 5
// 156.601 us; speedup vs baseline: 1.1243x; 1.1243x over previous
//
#include <hip/hip_runtime.h>

// Problem constants
#define BB 8
#define QQ 128
#define KK 1024
#define DD 256
#define HH 256

// A·V split-K config
#define KSPLIT 8
#define KCH (KK / KSPLIT)   // 128
#define QT 8                // q rows per av block

#define TWO_LOG2E     2.8853900817779268f
#define NEG_TWO_LOG2E -2.8853900817779268f

// ---------------------------------------------------------------------------
// K1: fused Q+K projection with exp2 epilogue (REVERTED to 64x64 tile:
// grid 576 = 2.25 blocks/CU; R3's 64x128 tile gave 288 blocks = 1.1/CU and
// went latency-bound at 47 us, VALUBusy 27%).
//   eproj[r][h] = exp2( TWO_LOG2E * sum_d A[r][d] * W[h][d] )
// ---------------------------------------------------------------------------
__global__ __launch_bounds__(256) void proj_kernel(const float* __restrict__ queries,
                                                   const float* __restrict__ keys,
                                                   const float* __restrict__ Wq,
                                                   const float* __restrict__ Wk,
                                                   float* __restrict__ eproj) {
    __shared__ float As[64][68];  // pad 68: <=2-way bank pattern (free)
    __shared__ float Ws[64][68];
    const int t  = threadIdx.x;
    const int tr = t & 15;        // rows {tr+16i}
    const int th = t >> 4;        // hs   {th+16i}
    const int r0 = blockIdx.x * 64;
    const int h0 = blockIdx.y * 64;
    const bool isQ = (r0 < BB * QQ);
    const float* A = isQ ? (queries + (size_t)r0 * DD)
                         : (keys + (size_t)(r0 - BB * QQ) * DD);
    const float* W = isQ ? Wq : Wk;

    float acc[4][4] = {};

    for (int dc = 0; dc < DD; dc += 64) {
#pragma unroll
        for (int i = 0; i < 4; ++i) {
            int fi  = t + 256 * i;        // 0..1023 float4 slots
            int row = fi >> 4;            // 0..63
            int c4  = (fi & 15) << 2;     // 0..60
            *(float4*)&As[row][c4] = *(const float4*)&A[(size_t)row * DD + dc + c4];
            *(float4*)&Ws[row][c4] = *(const float4*)&W[(size_t)(h0 + row) * DD + dc + c4];
        }
        __syncthreads();
#pragma unroll 4
        for (int dd = 0; dd < 64; dd += 4) {
            float4 a4[4], w4[4];
#pragma unroll
            for (int i = 0; i < 4; ++i) a4[i] = *(float4*)&As[tr + 16 * i][dd];
#pragma unroll
            for (int i = 0; i < 4; ++i) w4[i] = *(float4*)&Ws[th + 16 * i][dd];
#pragma unroll
            for (int ri = 0; ri < 4; ++ri)
#pragma unroll
                for (int hi = 0; hi < 4; ++hi) {
                    acc[ri][hi] += a4[ri].x * w4[hi].x + a4[ri].y * w4[hi].y +
                                   a4[ri].z * w4[hi].z + a4[ri].w * w4[hi].w;
                }
        }
        __syncthreads();
    }
#pragma unroll
    for (int ri = 0; ri < 4; ++ri)
#pragma unroll
        for (int hi = 0; hi < 4; ++hi) {
            eproj[(size_t)(r0 + tr + 16 * ri) * HH + h0 + th + 16 * hi] =
                __builtin_amdgcn_exp2f(TWO_LOG2E * acc[ri][hi]);
        }
}

// ---------------------------------------------------------------------------
// K2: unnormalized masked attention weights.
//   acc = sum_h w_v[h] * rcp(eq[b,q,h]*ek[b,k,h] + 1)
//   p = (k < vl) ? exp2(-2log2e * acc) : 0 ;  vl==0 -> p=1 (uniform, ref behavior)
// LDS-throughput-aware shape: 32q x 64k tile, thread = 2q x 4k. w_v read via
// wave-uniform scalar loads (s_load_dwordx4), NOT LDS: 6 b128 per 32
// thread-terms = 2.25 LDS-cyc/term-wave vs trans floor 2.0. Single-buffered.
// Grid 16x4x8 = 512 blocks = 2/CU, 26 KB LDS.
// ---------------------------------------------------------------------------
__global__ __launch_bounds__(256) void score_kernel(const float* __restrict__ eproj,
                                                    const float* __restrict__ wv,
                                                    const int* __restrict__ vlen,
                                                    float* __restrict__ p) {
    __shared__ float qs[32][68];
    __shared__ float ks_[64][68];
    const int t  = threadIdx.x;
    const int tk = t & 15;   // k's = {tk+16j, j<4}
    const int tq = t >> 4;   // q's = {tq, tq+16}
    const int b  = blockIdx.z;
    const int q0 = blockIdx.y * 32;
    const int k0 = blockIdx.x * 64;

    const float* qpB = eproj + ((size_t)(b * QQ + q0)) * HH;
    const float* kpB = eproj + ((size_t)(BB * QQ + b * KK + k0)) * HH;

    float acc[2][4] = {};

    for (int hc = 0; hc < HH; hc += 64) {
#pragma unroll
        for (int i = 0; i < 2; ++i) {
            int fi = t + 256 * i; int row = fi >> 4; int c4 = (fi & 15) << 2;
            *(float4*)&qs[row][c4] = *(const float4*)&qpB[(size_t)row * HH + hc + c4];
        }
#pragma unroll
        for (int i = 0; i < 4; ++i) {
            int fi = t + 256 * i; int row = fi >> 4; int c4 = (fi & 15) << 2;
            *(float4*)&ks_[row][c4] = *(const float4*)&kpB[(size_t)row * HH + hc + c4];
        }
        __syncthreads();

#pragma unroll 4
        for (int hh = 0; hh < 64; hh += 4) {
            // wave-uniform address -> scalar load; v_fmac takes SGPR operand
            const float4 w4 = *(const float4*)&wv[hc + hh];
            const float* wa = (const float*)&w4;
            float4 q4[2], k4[4];
            q4[0] = *(float4*)&qs[tq][hh];
            q4[1] = *(float4*)&qs[tq + 16][hh];
#pragma unroll
            for (int j = 0; j < 4; ++j) k4[j] = *(float4*)&ks_[tk + 16 * j][hh];
#pragma unroll
            for (int i = 0; i < 2; ++i) {
                const float* qa = (const float*)&q4[i];
#pragma unroll
                for (int j = 0; j < 4; ++j) {
                    const float* ka = (const float*)&k4[j];
#pragma unroll
                    for (int cc = 0; cc < 4; ++cc) {
                        float d = __builtin_fmaf(qa[cc], ka[cc], 1.0f);
                        acc[i][j] += wa[cc] * __builtin_amdgcn_rcpf(d);
                    }
                }
            }
        }
        __syncthreads();
    }

    const int vl = vlen[b];
#pragma unroll
    for (int i = 0; i < 2; ++i)
#pragma unroll
        for (int j = 0; j < 4; ++j) {
            int q = q0 + tq + 16 * i;
            int k = k0 + tk + 16 * j;
            float pv;
            if (vl == 0) pv = 1.0f;   // all-masked row -> uniform attn (ref behavior)
            else pv = (k < vl) ? __builtin_amdgcn_exp2f(NEG_TWO_LOG2E * acc[i][j])
                               : 0.0f;
            p[((size_t)b * QQ + q) * KK + k] = pv;
        }
}

// ---------------------------------------------------------------------------
// K3: split-K partial A·V on unnormalized p, plus per-chunk row sums.
// Block = (ks, q-tile of 8, b); thread t owns d-column t. 8-deep V prefetch.
// ---------------------------------------------------------------------------
__global__ __launch_bounds__(256) void av_partial(const float* __restrict__ p,
                                                  const float* __restrict__ V,
                                                  float* __restrict__ partial,
                                                  float* __restrict__ psum) {
    __shared__ float a_s[QT][KCH];     // [8][128]
    const int t   = threadIdx.x;       // d index 0..255
    const int ksb = blockIdx.x;        // k-chunk
    const int q0  = blockIdx.y * QT;
    const int b   = blockIdx.z;
    const int kc0 = ksb * KCH;

    const float* pB = p + ((size_t)b * QQ + q0) * KK + kc0;
    const float* VB = V + ((size_t)b * KK + kc0) * DD;

    {   // stage p chunk: 1024 floats = 256 float4, conflict-free
        int qi = t >> 5;
        int k4 = (t & 31) << 2;
        *(float4*)&a_s[qi][k4] = *(const float4*)&pB[(size_t)qi * KK + k4];
    }
    __syncthreads();

    // per-(b,q) chunk sum of p (for softmax denominator)
    if (t < QT) {
        float s = 0.f;
        for (int x = 0; x < KCH; x += 4) {
            float4 v = *(float4*)&a_s[t][x];
            s += v.x + v.y + v.z + v.w;
        }
        psum[((size_t)ksb * BB + b) * QQ + q0 + t] = s;
    }

    float acc[QT] = {};
    float vc[8], vn[8];
#pragma unroll
    for (int j = 0; j < 8; ++j) vc[j] = VB[(size_t)j * DD + t];

    for (int kg = 0; kg < KCH; kg += 8) {
        if (kg + 8 < KCH) {
#pragma unroll
            for (int j = 0; j < 8; ++j) vn[j] = VB[(size_t)(kg + 8 + j) * DD + t];
        }
#pragma unroll
        for (int qi = 0; qi < QT; ++qi) {
            float4 a0 = *(float4*)&a_s[qi][kg];       // broadcast reads (bank-cheap)
            float4 a1 = *(float4*)&a_s[qi][kg + 4];
            acc[qi] += a0.x * vc[0] + a0.y * vc[1] + a0.z * vc[2] + a0.w * vc[3] +
                       a1.x * vc[4] + a1.y * vc[5] + a1.z * vc[6] + a1.w * vc[7];
        }
#pragma unroll
        for (int j = 0; j < 8; ++j) vc[j] = vn[j];
    }

#pragma unroll
    for (int qi = 0; qi < QT; ++qi) {
        partial[(size_t)ksb * (BB * QQ * DD) +
                ((size_t)b * QQ + q0 + qi) * DD + t] = acc[qi];
    }
}

// ---------------------------------------------------------------------------
// K4: reduce partials and normalize by the row sum S. float4 per thread.
// ---------------------------------------------------------------------------
__global__ __launch_bounds__(256) void av_reduce(const float* __restrict__ partial,
                                                 const float* __restrict__ psum,
                                                 float* __restrict__ out) {
    const int i  = blockIdx.x * 256 + threadIdx.x;   // float4 index, 65536 total
    const int bq = i >> 6;                           // / (DD/4)

    float S = 0.f;
#pragma unroll
    for (int ks = 0; ks < KSPLIT; ++ks) S += psum[(size_t)ks * (BB * QQ) + bq];

    const float4* p4 = (const float4*)partial;
    const int stride4 = BB * QQ * DD / 4;            // 65536
    float4 s = p4[i];
#pragma unroll
    for (int ks = 1; ks < KSPLIT; ++ks) {
        float4 x = p4[(size_t)ks * stride4 + i];
        s.x += x.x; s.y += x.y; s.z += x.z; s.w += x.w;
    }
    const float inv = 1.0f / S;   // S>0 always: p>=8e-12 unmasked, vl==0 -> p=1
    s.x *= inv; s.y *= inv; s.z *= inv; s.w *= inv;
    ((float4*)out)[i] = s;
}

// ---------------------------------------------------------------------------
extern "C" void kernel_launch(void* const* d_in, const int* in_sizes, int n_in,
                              void* d_out, int out_size, void* d_ws, size_t ws_size,
                              hipStream_t stream) {
    const float* queries = (const float*)d_in[0];   // [B,Q,D]
    const float* keys    = (const float*)d_in[1];   // [B,K,D]
    const float* values  = (const float*)d_in[2];   // [B,K,D]
    const float* W_q     = (const float*)d_in[3];   // [H,D]
    const float* W_k     = (const float*)d_in[4];   // [H,D]
    const float* w_v     = (const float*)d_in[5];   // [H]
    const int*   vlen    = (const int*)d_in[6];     // [B]
    float* out = (float*)d_out;

    float* ws    = (float*)d_ws;
    float* eproj = ws;                                      // (B*Q + B*K)*H = 2359296
    float* p     = ws + (size_t)(BB * QQ + BB * KK) * HH;   // B*Q*K = 1048576
    float* psum  = p + (size_t)BB * QQ * KK;                // KSPLIT*B*Q = 8192
    // partial aliases eproj (dead after score_kernel): KSPLIT*B*Q*D = 2097152 fits
    float* partial = ws;

    // Fused Q+K projection with exp2 epilogue (64x64 tiles, 576 blocks)
    proj_kernel<<<dim3((BB * QQ + BB * KK) / 64, HH / 64, 1), 256, 0, stream>>>(
        queries, keys, W_q, W_k, eproj);

    // Unnormalized masked attention weights (scalar-w, 2q x 4k, single-buffer)
    score_kernel<<<dim3(KK / 64, QQ / 32, BB), 256, 0, stream>>>(eproj, w_v, vlen, p);

    // p @ V split-K + chunk row sums
    av_partial<<<dim3(KSPLIT, QQ / QT, BB), 256, 0, stream>>>(p, values, partial, psum);

    // Reduce + softmax normalization
    av_reduce<<<dim3(BB * QQ * DD / 4 / 256, 1, 1), 256, 0, stream>>>(partial, psum, out);
}

// Round 6
// 150.608 us; speedup vs baseline: 1.1690x; 1.0398x over previous
//
#include <hip/hip_runtime.h>

// Problem constants
#define BB 8
#define QQ 128
#define KK 1024
#define DD 256
#define HH 256

// A·V split-K config
#define KSPLIT 8
#define KCH (KK / KSPLIT)   // 128
#define QT 8                // q rows per av block

#define TWO_LOG2E     2.8853900817779268f
#define NEG_TWO_LOG2E -2.8853900817779268f

// ---------------------------------------------------------------------------
// K1: fused Q+K projection with exp2 epilogue (64x64 tile, 576 blocks).
//   eproj[r][h] = exp2( TWO_LOG2E * sum_d A[r][d] * W[h][d] )
// MASK SKIP: key blocks whose 64 k-rows are all >= vl[b] are never read by
// score's unmasked path -> early return (uniform branch). Skipped rows keep
// the 0xAA ws poison (~ -3e-13f); score's boundary tiles read them into
// d = eq*ek+1 ~= 1.0 -> rcp safe, result masked at write. Bit-identical out.
// ---------------------------------------------------------------------------
__global__ __launch_bounds__(256) void proj_kernel(const float* __restrict__ queries,
                                                   const float* __restrict__ keys,
                                                   const float* __restrict__ Wq,
                                                   const float* __restrict__ Wk,
                                                   const int* __restrict__ vlen,
                                                   float* __restrict__ eproj) {
    const int r0 = blockIdx.x * 64;
    const bool isQ = (r0 < BB * QQ);
    if (!isQ) {
        // key block: 64 consecutive k of one b (K=1024 = 16 blocks per b)
        const int kb = (r0 - BB * QQ) >> 6;      // key-block index
        const int b  = kb >> 4;
        const int k0 = (kb & 15) << 6;           // local k of first row
        const int vl = vlen[b];
        if (k0 >= vl) return;                    // fully masked (vl==0 too)
    }

    __shared__ float As[64][68];  // pad 68: <=2-way bank pattern (free)
    __shared__ float Ws[64][68];
    const int t  = threadIdx.x;
    const int tr = t & 15;        // rows {tr+16i}
    const int th = t >> 4;        // hs   {th+16i}
    const int h0 = blockIdx.y * 64;
    const float* A = isQ ? (queries + (size_t)r0 * DD)
                         : (keys + (size_t)(r0 - BB * QQ) * DD);
    const float* W = isQ ? Wq : Wk;

    float acc[4][4] = {};

    for (int dc = 0; dc < DD; dc += 64) {
#pragma unroll
        for (int i = 0; i < 4; ++i) {
            int fi  = t + 256 * i;        // 0..1023 float4 slots
            int row = fi >> 4;            // 0..63
            int c4  = (fi & 15) << 2;     // 0..60
            *(float4*)&As[row][c4] = *(const float4*)&A[(size_t)row * DD + dc + c4];
            *(float4*)&Ws[row][c4] = *(const float4*)&W[(size_t)(h0 + row) * DD + dc + c4];
        }
        __syncthreads();
#pragma unroll 4
        for (int dd = 0; dd < 64; dd += 4) {
            float4 a4[4], w4[4];
#pragma unroll
            for (int i = 0; i < 4; ++i) a4[i] = *(float4*)&As[tr + 16 * i][dd];
#pragma unroll
            for (int i = 0; i < 4; ++i) w4[i] = *(float4*)&Ws[th + 16 * i][dd];
#pragma unroll
            for (int ri = 0; ri < 4; ++ri)
#pragma unroll
                for (int hi = 0; hi < 4; ++hi) {
                    acc[ri][hi] += a4[ri].x * w4[hi].x + a4[ri].y * w4[hi].y +
                                   a4[ri].z * w4[hi].z + a4[ri].w * w4[hi].w;
                }
        }
        __syncthreads();
    }
#pragma unroll
    for (int ri = 0; ri < 4; ++ri)
#pragma unroll
        for (int hi = 0; hi < 4; ++hi) {
            eproj[(size_t)(r0 + tr + 16 * ri) * HH + h0 + th + 16 * hi] =
                __builtin_amdgcn_exp2f(TWO_LOG2E * acc[ri][hi]);
        }
}

// ---------------------------------------------------------------------------
// K2: unnormalized masked attention weights.
//   acc = sum_h w_v[h] * rcp(eq[b,q,h]*ek[b,k,h] + 1)
//   p = (k < vl) ? exp2(-2log2e * acc) : 0 ;  vl==0 -> p=1 (uniform, ref)
// MASK SKIP: fully-masked tiles (k0 >= vl) write constants and skip the
// h-loop entirely (the dominant trans work halves in expectation).
// 32q x 64k tile, thread = 2q x 4k, scalar w_v loads. 512 blocks.
// ---------------------------------------------------------------------------
__global__ __launch_bounds__(256) void score_kernel(const float* __restrict__ eproj,
                                                    const float* __restrict__ wv,
                                                    const int* __restrict__ vlen,
                                                    float* __restrict__ p) {
    __shared__ float qs[32][68];
    __shared__ float ks_[64][68];
    const int t  = threadIdx.x;
    const int tk = t & 15;   // k's = {tk+16j, j<4}
    const int tq = t >> 4;   // q's = {tq, tq+16}
    const int b  = blockIdx.z;
    const int q0 = blockIdx.y * 32;
    const int k0 = blockIdx.x * 64;
    const int vl = vlen[b];

    if (k0 >= vl) {
        // fully masked tile: p = (vl==0 ? 1 : 0), no compute
        const float pv = (vl == 0) ? 1.0f : 0.0f;
#pragma unroll
        for (int i = 0; i < 2; ++i)
#pragma unroll
            for (int j = 0; j < 4; ++j) {
                int q = q0 + tq + 16 * i;
                int k = k0 + tk + 16 * j;
                p[((size_t)b * QQ + q) * KK + k] = pv;
            }
        return;
    }

    const float* qpB = eproj + ((size_t)(b * QQ + q0)) * HH;
    const float* kpB = eproj + ((size_t)(BB * QQ + b * KK + k0)) * HH;

    float acc[2][4] = {};

    for (int hc = 0; hc < HH; hc += 64) {
#pragma unroll
        for (int i = 0; i < 2; ++i) {
            int fi = t + 256 * i; int row = fi >> 4; int c4 = (fi & 15) << 2;
            *(float4*)&qs[row][c4] = *(const float4*)&qpB[(size_t)row * HH + hc + c4];
        }
#pragma unroll
        for (int i = 0; i < 4; ++i) {
            int fi = t + 256 * i; int row = fi >> 4; int c4 = (fi & 15) << 2;
            *(float4*)&ks_[row][c4] = *(const float4*)&kpB[(size_t)row * HH + hc + c4];
        }
        __syncthreads();

#pragma unroll 4
        for (int hh = 0; hh < 64; hh += 4) {
            // wave-uniform address -> scalar load; v_fmac takes SGPR operand
            const float4 w4 = *(const float4*)&wv[hc + hh];
            const float* wa = (const float*)&w4;
            float4 q4[2], k4[4];
            q4[0] = *(float4*)&qs[tq][hh];
            q4[1] = *(float4*)&qs[tq + 16][hh];
#pragma unroll
            for (int j = 0; j < 4; ++j) k4[j] = *(float4*)&ks_[tk + 16 * j][hh];
#pragma unroll
            for (int i = 0; i < 2; ++i) {
                const float* qa = (const float*)&q4[i];
#pragma unroll
                for (int j = 0; j < 4; ++j) {
                    const float* ka = (const float*)&k4[j];
#pragma unroll
                    for (int cc = 0; cc < 4; ++cc) {
                        float d = __builtin_fmaf(qa[cc], ka[cc], 1.0f);
                        acc[i][j] += wa[cc] * __builtin_amdgcn_rcpf(d);
                    }
                }
            }
        }
        __syncthreads();
    }

#pragma unroll
    for (int i = 0; i < 2; ++i)
#pragma unroll
        for (int j = 0; j < 4; ++j) {
            int q = q0 + tq + 16 * i;
            int k = k0 + tk + 16 * j;
            float pv = (k < vl) ? __builtin_amdgcn_exp2f(NEG_TWO_LOG2E * acc[i][j])
                                : 0.0f;
            p[((size_t)b * QQ + q) * KK + k] = pv;
        }
}

// ---------------------------------------------------------------------------
// K3: split-K partial A·V on unnormalized p, plus per-chunk row sums.
// Block = (ks, q-tile of 8, b); thread t owns d-column t. 8-deep V prefetch.
// MASK SKIP: fully-masked chunk (vl>0) -> zero partial/psum, no V loads.
// ---------------------------------------------------------------------------
__global__ __launch_bounds__(256) void av_partial(const float* __restrict__ p,
                                                  const float* __restrict__ V,
                                                  const int* __restrict__ vlen,
                                                  float* __restrict__ partial,
                                                  float* __restrict__ psum) {
    __shared__ float a_s[QT][KCH];     // [8][128]
    const int t   = threadIdx.x;       // d index 0..255
    const int ksb = blockIdx.x;        // k-chunk
    const int q0  = blockIdx.y * QT;
    const int b   = blockIdx.z;
    const int kc0 = ksb * KCH;
    const int vl  = vlen[b];

    if (vl > 0 && kc0 >= vl) {
        // fully masked chunk: p == 0 exactly -> zero outputs, skip all loads
#pragma unroll
        for (int qi = 0; qi < QT; ++qi)
            partial[(size_t)ksb * (BB * QQ * DD) +
                    ((size_t)b * QQ + q0 + qi) * DD + t] = 0.0f;
        if (t < QT) psum[((size_t)ksb * BB + b) * QQ + q0 + t] = 0.0f;
        return;
    }

    const float* pB = p + ((size_t)b * QQ + q0) * KK + kc0;
    const float* VB = V + ((size_t)b * KK + kc0) * DD;

    {   // stage p chunk: 1024 floats = 256 float4, conflict-free
        int qi = t >> 5;
        int k4 = (t & 31) << 2;
        *(float4*)&a_s[qi][k4] = *(const float4*)&pB[(size_t)qi * KK + k4];
    }
    __syncthreads();

    // per-(b,q) chunk sum of p (for softmax denominator)
    if (t < QT) {
        float s = 0.f;
        for (int x = 0; x < KCH; x += 4) {
            float4 v = *(float4*)&a_s[t][x];
            s += v.x + v.y + v.z + v.w;
        }
        psum[((size_t)ksb * BB + b) * QQ + q0 + t] = s;
    }

    float acc[QT] = {};
    float vc[8], vn[8];
#pragma unroll
    for (int j = 0; j < 8; ++j) vc[j] = VB[(size_t)j * DD + t];

    for (int kg = 0; kg < KCH; kg += 8) {
        if (kg + 8 < KCH) {
#pragma unroll
            for (int j = 0; j < 8; ++j) vn[j] = VB[(size_t)(kg + 8 + j) * DD + t];
        }
#pragma unroll
        for (int qi = 0; qi < QT; ++qi) {
            float4 a0 = *(float4*)&a_s[qi][kg];       // broadcast reads (bank-cheap)
            float4 a1 = *(float4*)&a_s[qi][kg + 4];
            acc[qi] += a0.x * vc[0] + a0.y * vc[1] + a0.z * vc[2] + a0.w * vc[3] +
                       a1.x * vc[4] + a1.y * vc[5] + a1.z * vc[6] + a1.w * vc[7];
        }
#pragma unroll
        for (int j = 0; j < 8; ++j) vc[j] = vn[j];
    }

#pragma unroll
    for (int qi = 0; qi < QT; ++qi) {
        partial[(size_t)ksb * (BB * QQ * DD) +
                ((size_t)b * QQ + q0 + qi) * DD + t] = acc[qi];
    }
}

// ---------------------------------------------------------------------------
// K4: reduce partials and normalize by the row sum S. float4 per thread.
// ---------------------------------------------------------------------------
__global__ __launch_bounds__(256) void av_reduce(const float* __restrict__ partial,
                                                 const float* __restrict__ psum,
                                                 float* __restrict__ out) {
    const int i  = blockIdx.x * 256 + threadIdx.x;   // float4 index, 65536 total
    const int bq = i >> 6;                           // / (DD/4)

    float S = 0.f;
#pragma unroll
    for (int ks = 0; ks < KSPLIT; ++ks) S += psum[(size_t)ks * (BB * QQ) + bq];

    const float4* p4 = (const float4*)partial;
    const int stride4 = BB * QQ * DD / 4;            // 65536
    float4 s = p4[i];
#pragma unroll
    for (int ks = 1; ks < KSPLIT; ++ks) {
        float4 x = p4[(size_t)ks * stride4 + i];
        s.x += x.x; s.y += x.y; s.z += x.z; s.w += x.w;
    }
    const float inv = 1.0f / S;   // S>0 always: p>=8e-12 unmasked, vl==0 -> p=1
    s.x *= inv; s.y *= inv; s.z *= inv; s.w *= inv;
    ((float4*)out)[i] = s;
}

// ---------------------------------------------------------------------------
extern "C" void kernel_launch(void* const* d_in, const int* in_sizes, int n_in,
                              void* d_out, int out_size, void* d_ws, size_t ws_size,
                              hipStream_t stream) {
    const float* queries = (const float*)d_in[0];   // [B,Q,D]
    const float* keys    = (const float*)d_in[1];   // [B,K,D]
    const float* values  = (const float*)d_in[2];   // [B,K,D]
    const float* W_q     = (const float*)d_in[3];   // [H,D]
    const float* W_k     = (const float*)d_in[4];   // [H,D]
    const float* w_v     = (const float*)d_in[5];   // [H]
    const int*   vlen    = (const int*)d_in[6];     // [B]
    float* out = (float*)d_out;

    float* ws    = (float*)d_ws;
    float* eproj = ws;                                      // (B*Q + B*K)*H = 2359296
    float* p     = ws + (size_t)(BB * QQ + BB * KK) * HH;   // B*Q*K = 1048576
    float* psum  = p + (size_t)BB * QQ * KK;                // KSPLIT*B*Q = 8192
    // partial aliases eproj (dead after score_kernel): KSPLIT*B*Q*D = 2097152 fits
    float* partial = ws;

    // Fused Q+K projection with exp2 epilogue, masked key blocks skipped
    proj_kernel<<<dim3((BB * QQ + BB * KK) / 64, HH / 64, 1), 256, 0, stream>>>(
        queries, keys, W_q, W_k, vlen, eproj);

    // Unnormalized masked attention weights, fully-masked tiles skipped
    score_kernel<<<dim3(KK / 64, QQ / 32, BB), 256, 0, stream>>>(eproj, w_v, vlen, p);

    // p @ V split-K + chunk row sums, fully-masked chunks skipped
    av_partial<<<dim3(KSPLIT, QQ / QT, BB), 256, 0, stream>>>(p, values, vlen, partial, psum);

    // Reduce + softmax normalization
    av_reduce<<<dim3(BB * QQ * DD / 4 / 256, 1, 1), 256, 0, stream>>>(partial, psum, out);
}

// Round 7
// 146.151 us; speedup vs baseline: 1.2047x; 1.0305x over previous
//
#include <hip/hip_runtime.h>

// Problem constants
#define BB 8
#define QQ 128
#define KK 1024
#define DD 256
#define HH 256

// scoreav split-K: 16 chunks of 64 k
#define KSP 16
#define KCH 64

#define TWO_LOG2E     2.8853900817779268f
#define NEG_TWO_LOG2E -2.8853900817779268f

// ---------------------------------------------------------------------------
// K1: fused Q+K projection with exp2 epilogue (64x64 tile, 576 blocks).
//   eproj[r][h] = exp2( TWO_LOG2E * sum_d A[r][d] * W[h][d] )
// MASK SKIP: key blocks fully >= vl[b] are never read unmasked -> early out.
// ---------------------------------------------------------------------------
__global__ __launch_bounds__(256) void proj_kernel(const float* __restrict__ queries,
                                                   const float* __restrict__ keys,
                                                   const float* __restrict__ Wq,
                                                   const float* __restrict__ Wk,
                                                   const int* __restrict__ vlen,
                                                   float* __restrict__ eproj) {
    const int r0 = blockIdx.x * 64;
    const bool isQ = (r0 < BB * QQ);
    if (!isQ) {
        const int kb = (r0 - BB * QQ) >> 6;      // key-block index
        const int b  = kb >> 4;
        const int k0 = (kb & 15) << 6;
        if (k0 >= vlen[b]) return;               // fully masked (vl==0 too)
    }

    __shared__ float As[64][68];  // pad 68: <=2-way bank pattern (free)
    __shared__ float Ws[64][68];
    const int t  = threadIdx.x;
    const int tr = t & 15;
    const int th = t >> 4;
    const int h0 = blockIdx.y * 64;
    const float* A = isQ ? (queries + (size_t)r0 * DD)
                         : (keys + (size_t)(r0 - BB * QQ) * DD);
    const float* W = isQ ? Wq : Wk;

    float acc[4][4] = {};

    for (int dc = 0; dc < DD; dc += 64) {
#pragma unroll
        for (int i = 0; i < 4; ++i) {
            int fi  = t + 256 * i;
            int row = fi >> 4;
            int c4  = (fi & 15) << 2;
            *(float4*)&As[row][c4] = *(const float4*)&A[(size_t)row * DD + dc + c4];
            *(float4*)&Ws[row][c4] = *(const float4*)&W[(size_t)(h0 + row) * DD + dc + c4];
        }
        __syncthreads();
#pragma unroll 4
        for (int dd = 0; dd < 64; dd += 4) {
            float4 a4[4], w4[4];
#pragma unroll
            for (int i = 0; i < 4; ++i) a4[i] = *(float4*)&As[tr + 16 * i][dd];
#pragma unroll
            for (int i = 0; i < 4; ++i) w4[i] = *(float4*)&Ws[th + 16 * i][dd];
#pragma unroll
            for (int ri = 0; ri < 4; ++ri)
#pragma unroll
                for (int hi = 0; hi < 4; ++hi) {
                    acc[ri][hi] += a4[ri].x * w4[hi].x + a4[ri].y * w4[hi].y +
                                   a4[ri].z * w4[hi].z + a4[ri].w * w4[hi].w;
                }
        }
        __syncthreads();
    }
#pragma unroll
    for (int ri = 0; ri < 4; ++ri)
#pragma unroll
        for (int hi = 0; hi < 4; ++hi) {
            eproj[(size_t)(r0 + tr + 16 * ri) * HH + h0 + th + 16 * hi] =
                __builtin_amdgcn_exp2f(TWO_LOG2E * acc[ri][hi]);
        }
}

// ---------------------------------------------------------------------------
// K2: FUSED score + A*V chunk kernel.
// Block = (ksb in [0,16), 32-q tile, b). Phase 1 (score): p tile 32q x 64k,
//   acc = sum_h w_v[h]*rcp(eq*ek+1);  pv = (k<vl) ? exp2(-2log2e*acc) : 0
//   (vl==0 -> pv=1). pv goes to LDS pT[k][q] (never to global). psum via
//   16-lane shuffle reduce. Phase 2 (av): thread = (4d x 8q), per k:
//   2 broadcast b128 pT reads + coalesced float4 V load + 32 FMA
//   (rho = 0.0625 b128/FMA vs 0.25 in the old av_partial).
// MASK SKIP: chunk fully masked & vl>0 -> zero partial/psum, no compute.
// ---------------------------------------------------------------------------
__global__ __launch_bounds__(256) void scoreav_kernel(const float* __restrict__ eproj,
                                                      const float* __restrict__ wv,
                                                      const int* __restrict__ vlen,
                                                      const float* __restrict__ V,
                                                      float* __restrict__ partial,
                                                      float* __restrict__ psum) {
    __shared__ float qs[32][68];
    __shared__ float ks_[64][68];
    __shared__ float pT[KCH][36];   // [k][q], row = 144 B (16B-aligned)
    const int t   = threadIdx.x;
    const int tk  = t & 15;         // k's = {tk+16j, j<4}
    const int tq  = t >> 4;         // q's = {tq, tq+16}
    const int ksb = blockIdx.x;
    const int q0  = blockIdx.y * 32;
    const int b   = blockIdx.z;
    const int k0  = ksb * KCH;
    const int vl  = vlen[b];

    const int d4 = (t & 63) << 2;   // av-phase d base (0..252)
    const int qh = (t >> 6) << 3;   // av-phase q base within tile (0,8,16,24)

    if (vl > 0 && k0 >= vl) {
        // fully masked chunk: p == 0 exactly -> zero outputs, skip everything
        float4 z = {0.f, 0.f, 0.f, 0.f};
#pragma unroll
        for (int qi = 0; qi < 8; ++qi) {
            int q = q0 + qh + qi;
            *(float4*)&partial[(((size_t)ksb * BB + b) * QQ + q) * DD + d4] = z;
        }
        if (t < 32) psum[((size_t)ksb * BB + b) * QQ + q0 + t] = 0.f;
        return;
    }

    // ---- phase 1: score ----
    float acc[2][4] = {};
    if (vl > 0) {   // vl==0 -> pv=1 uniform, skip all score compute
        const float* qpB = eproj + (size_t)(b * QQ + q0) * HH;
        const float* kpB = eproj + (size_t)(BB * QQ + b * KK + k0) * HH;

        for (int hc = 0; hc < HH; hc += 64) {
#pragma unroll
            for (int i = 0; i < 2; ++i) {
                int fi = t + 256 * i; int row = fi >> 4; int c4 = (fi & 15) << 2;
                *(float4*)&qs[row][c4] = *(const float4*)&qpB[(size_t)row * HH + hc + c4];
            }
#pragma unroll
            for (int i = 0; i < 4; ++i) {
                int fi = t + 256 * i; int row = fi >> 4; int c4 = (fi & 15) << 2;
                *(float4*)&ks_[row][c4] = *(const float4*)&kpB[(size_t)row * HH + hc + c4];
            }
            __syncthreads();

#pragma unroll 4
            for (int hh = 0; hh < 64; hh += 4) {
                const float4 w4 = *(const float4*)&wv[hc + hh];  // scalar loads
                const float* wa = (const float*)&w4;
                float4 q4[2], k4[4];
                q4[0] = *(float4*)&qs[tq][hh];
                q4[1] = *(float4*)&qs[tq + 16][hh];
#pragma unroll
                for (int j = 0; j < 4; ++j) k4[j] = *(float4*)&ks_[tk + 16 * j][hh];
#pragma unroll
                for (int i = 0; i < 2; ++i) {
                    const float* qa = (const float*)&q4[i];
#pragma unroll
                    for (int j = 0; j < 4; ++j) {
                        const float* ka = (const float*)&k4[j];
#pragma unroll
                        for (int cc = 0; cc < 4; ++cc) {
                            float d = __builtin_fmaf(qa[cc], ka[cc], 1.0f);
                            acc[i][j] += wa[cc] * __builtin_amdgcn_rcpf(d);
                        }
                    }
                }
            }
            __syncthreads();
        }
    }

    // epilogue: masked pv -> pT[k][q]; row sums via 16-lane shuffle
    float sj[2] = {0.f, 0.f};
#pragma unroll
    for (int i = 0; i < 2; ++i)
#pragma unroll
        for (int j = 0; j < 4; ++j) {
            int kg = k0 + tk + 16 * j;
            float pv;
            if (vl == 0) pv = 1.0f;
            else pv = (kg < vl) ? __builtin_amdgcn_exp2f(NEG_TWO_LOG2E * acc[i][j])
                                : 0.0f;
            pT[tk + 16 * j][tq + 16 * i] = pv;   // exact 2-way banks (free)
            sj[i] += pv;
        }
#pragma unroll
    for (int off = 1; off < 16; off <<= 1) {
        sj[0] += __shfl_xor(sj[0], off);
        sj[1] += __shfl_xor(sj[1], off);
    }
    if (tk == 0) {
        psum[((size_t)ksb * BB + b) * QQ + q0 + tq]      = sj[0];
        psum[((size_t)ksb * BB + b) * QQ + q0 + tq + 16] = sj[1];
    }
    __syncthreads();

    // ---- phase 2: av ----
    const float* VB = V + ((size_t)b * KK + k0) * DD;
    float4 acc4[8] = {};
#pragma unroll 4
    for (int k = 0; k < KCH; ++k) {
        float4 v4 = *(const float4*)&VB[(size_t)k * DD + d4];   // coalesced
        float4 p0 = *(float4*)&pT[k][qh];        // broadcast (wave-uniform addr)
        float4 p1 = *(float4*)&pT[k][qh + 4];
        acc4[0].x += p0.x * v4.x; acc4[0].y += p0.x * v4.y; acc4[0].z += p0.x * v4.z; acc4[0].w += p0.x * v4.w;
        acc4[1].x += p0.y * v4.x; acc4[1].y += p0.y * v4.y; acc4[1].z += p0.y * v4.z; acc4[1].w += p0.y * v4.w;
        acc4[2].x += p0.z * v4.x; acc4[2].y += p0.z * v4.y; acc4[2].z += p0.z * v4.z; acc4[2].w += p0.z * v4.w;
        acc4[3].x += p0.w * v4.x; acc4[3].y += p0.w * v4.y; acc4[3].z += p0.w * v4.z; acc4[3].w += p0.w * v4.w;
        acc4[4].x += p1.x * v4.x; acc4[4].y += p1.x * v4.y; acc4[4].z += p1.x * v4.z; acc4[4].w += p1.x * v4.w;
        acc4[5].x += p1.y * v4.x; acc4[5].y += p1.y * v4.y; acc4[5].z += p1.y * v4.z; acc4[5].w += p1.y * v4.w;
        acc4[6].x += p1.z * v4.x; acc4[6].y += p1.z * v4.y; acc4[6].z += p1.z * v4.z; acc4[6].w += p1.z * v4.w;
        acc4[7].x += p1.w * v4.x; acc4[7].y += p1.w * v4.y; acc4[7].z += p1.w * v4.z; acc4[7].w += p1.w * v4.w;
    }

#pragma unroll
    for (int qi = 0; qi < 8; ++qi) {
        int q = q0 + qh + qi;
        *(float4*)&partial[(((size_t)ksb * BB + b) * QQ + q) * DD + d4] = acc4[qi];
    }
}

// ---------------------------------------------------------------------------
// K3: reduce the KSP partials, normalize by S. One (b,q,d4) per thread.
// ---------------------------------------------------------------------------
__global__ __launch_bounds__(256) void av_reduce(const float* __restrict__ partial,
                                                 const float* __restrict__ psum,
                                                 float* __restrict__ out) {
    const int i  = blockIdx.x * 256 + threadIdx.x;   // float4 index, 65536 total
    const int bq = i >> 6;                           // b*QQ + q

    float S = 0.f;
#pragma unroll
    for (int ks = 0; ks < KSP; ++ks) S += psum[(size_t)ks * (BB * QQ) + bq];

    const float4* p4 = (const float4*)partial;
    const int stride4 = BB * QQ * DD / 4;            // 65536
    float4 s = p4[i];
#pragma unroll
    for (int ks = 1; ks < KSP; ++ks) {
        float4 x = p4[(size_t)ks * stride4 + i];
        s.x += x.x; s.y += x.y; s.z += x.z; s.w += x.w;
    }
    const float inv = 1.0f / S;   // S>0 always: p>=8e-12 unmasked, vl==0 -> p=1
    s.x *= inv; s.y *= inv; s.z *= inv; s.w *= inv;
    ((float4*)out)[i] = s;
}

// ---------------------------------------------------------------------------
extern "C" void kernel_launch(void* const* d_in, const int* in_sizes, int n_in,
                              void* d_out, int out_size, void* d_ws, size_t ws_size,
                              hipStream_t stream) {
    const float* queries = (const float*)d_in[0];   // [B,Q,D]
    const float* keys    = (const float*)d_in[1];   // [B,K,D]
    const float* values  = (const float*)d_in[2];   // [B,K,D]
    const float* W_q     = (const float*)d_in[3];   // [H,D]
    const float* W_k     = (const float*)d_in[4];   // [H,D]
    const float* w_v     = (const float*)d_in[5];   // [H]
    const int*   vlen    = (const int*)d_in[6];     // [B]
    float* out = (float*)d_out;

    float* ws      = (float*)d_ws;
    float* eproj   = ws;                                    // (B*Q+B*K)*H = 2359296
    float* psum    = eproj + (size_t)(BB * QQ + BB * KK) * HH;  // KSP*B*Q = 16384
    float* partial = psum + (size_t)KSP * BB * QQ;          // KSP*B*Q*D = 16.8 MB
    // NOTE: partial must NOT alias eproj (scoreav reads eproj while writing
    // partial). Total ws use ~26 MB of 256 MB.

    // Fused Q+K projection with exp2 epilogue, masked key blocks skipped
    proj_kernel<<<dim3((BB * QQ + BB * KK) / 64, HH / 64, 1), 256, 0, stream>>>(
        queries, keys, W_q, W_k, vlen, eproj);

    // Fused score + A*V chunk (p never touches global), masked chunks skipped
    scoreav_kernel<<<dim3(KSP, QQ / 32, BB), 256, 0, stream>>>(
        eproj, w_v, vlen, values, partial, psum);

    // Reduce + softmax normalization
    av_reduce<<<dim3(BB * QQ * DD / 4 / 256, 1, 1), 256, 0, stream>>>(partial, psum, out);
}

// Round 8
// 143.577 us; speedup vs baseline: 1.2263x; 1.0179x over previous
//
#include <hip/hip_runtime.h>

// Problem constants
#define BB 8
#define QQ 128
#define KK 1024
#define DD 256
#define HH 256

// scoreav split-K: 32 chunks of 32 k (fine granularity -> ~540 dense items)
#define KSP 32
#define KCH 32

#define TWO_LOG2E     2.8853900817779268f
#define NEG_TWO_LOG2E -2.8853900817779268f

// ---------------------------------------------------------------------------
// K1: fused Q+K projection with exp2 epilogue (64x64 tile, 576 blocks).
//   eproj[r][h] = exp2( TWO_LOG2E * sum_d A[r][d] * W[h][d] )
// MASK SKIP: key blocks fully >= vl[b] -> early out. Coverage ceil(vl/64)*64
// always >= scoreav's max read ceil(vl/32)*32, so no poison is ever read.
// ---------------------------------------------------------------------------
__global__ __launch_bounds__(256) void proj_kernel(const float* __restrict__ queries,
                                                   const float* __restrict__ keys,
                                                   const float* __restrict__ Wq,
                                                   const float* __restrict__ Wk,
                                                   const int* __restrict__ vlen,
                                                   float* __restrict__ eproj) {
    const int r0 = blockIdx.x * 64;
    const bool isQ = (r0 < BB * QQ);
    if (!isQ) {
        const int kb = (r0 - BB * QQ) >> 6;      // key-block index
        const int b  = kb >> 4;
        const int k0 = (kb & 15) << 6;
        if (k0 >= vlen[b]) return;               // fully masked (vl==0 too)
    }

    __shared__ float As[64][68];  // pad 68: <=2-way bank pattern (free)
    __shared__ float Ws[64][68];
    const int t  = threadIdx.x;
    const int tr = t & 15;
    const int th = t >> 4;
    const int h0 = blockIdx.y * 64;
    const float* A = isQ ? (queries + (size_t)r0 * DD)
                         : (keys + (size_t)(r0 - BB * QQ) * DD);
    const float* W = isQ ? Wq : Wk;

    float acc[4][4] = {};

    for (int dc = 0; dc < DD; dc += 64) {
#pragma unroll
        for (int i = 0; i < 4; ++i) {
            int fi  = t + 256 * i;
            int row = fi >> 4;
            int c4  = (fi & 15) << 2;
            *(float4*)&As[row][c4] = *(const float4*)&A[(size_t)row * DD + dc + c4];
            *(float4*)&Ws[row][c4] = *(const float4*)&W[(size_t)(h0 + row) * DD + dc + c4];
        }
        __syncthreads();
#pragma unroll 4
        for (int dd = 0; dd < 64; dd += 4) {
            float4 a4[4], w4[4];
#pragma unroll
            for (int i = 0; i < 4; ++i) a4[i] = *(float4*)&As[tr + 16 * i][dd];
#pragma unroll
            for (int i = 0; i < 4; ++i) w4[i] = *(float4*)&Ws[th + 16 * i][dd];
#pragma unroll
            for (int ri = 0; ri < 4; ++ri)
#pragma unroll
                for (int hi = 0; hi < 4; ++hi) {
                    acc[ri][hi] += a4[ri].x * w4[hi].x + a4[ri].y * w4[hi].y +
                                   a4[ri].z * w4[hi].z + a4[ri].w * w4[hi].w;
                }
        }
        __syncthreads();
    }
#pragma unroll
    for (int ri = 0; ri < 4; ++ri)
#pragma unroll
        for (int hi = 0; hi < 4; ++hi) {
            eproj[(size_t)(r0 + tr + 16 * ri) * HH + h0 + th + 16 * hi] =
                __builtin_amdgcn_exp2f(TWO_LOG2E * acc[ri][hi]);
        }
}

// ---------------------------------------------------------------------------
// K2: FUSED score + A*V with WORK COMPACTION.
// Dense items = (b, ksb < nch(b), qtile) where nch = vl==0 ? 32 : ceil(vl/32);
// block id mapped by an 8-step prefix scan of vlen (masked chunks simply
// don't exist). T ~ 540 working blocks = ~2.1/CU = ~8.5 waves/CU (vs 1
// working block/CU in R7 -> the 4x stall exposure seen as VALUBusy 25%).
// Phase 1 (score, 32q x 32k, thread = 2q x 2k):
//   acc = sum_h w_v[h]*rcp(eq*ek+1);  pv = (k<vl)?exp2(-2log2e*acc):0
//   (vl==0 -> pv=1); pv -> LDS pT[k][q]; psum via 16-lane shuffle.
// Phase 2 (av, thread = 4d x 8q): per k: 2 broadcast b128 + float4 V + 32 fmac.
// ---------------------------------------------------------------------------
__global__ __launch_bounds__(256) void scoreav_kernel(const float* __restrict__ eproj,
                                                      const float* __restrict__ wv,
                                                      const int* __restrict__ vlen,
                                                      const float* __restrict__ V,
                                                      float* __restrict__ partial,
                                                      float* __restrict__ psum) {
    // ---- work-item compaction (uniform, ~8 L2-hot scalar loads) ----
    int id = blockIdx.x;
    int b = 0;
    bool found = false;
#pragma unroll
    for (int bb = 0; bb < BB; ++bb) {
        if (!found) {
            int v = vlen[bb];
            int cnt = ((v == 0) ? KSP : ((v + KCH - 1) / KCH)) * 4;
            if (id < cnt) { b = bb; found = true; }
            else id -= cnt;
        }
    }
    if (!found) return;                  // beyond total work: vacate
    const int ksb = id >> 2;
    const int q0  = (id & 3) * 32;
    const int k0  = ksb * KCH;
    const int vl  = vlen[b];

    __shared__ float qs[32][68];
    __shared__ float ks_[32][68];
    __shared__ float pT[KCH][36];        // [k][q], 144 B rows
    const int t  = threadIdx.x;
    const int tk = t & 15;               // k's = {tk, tk+16}
    const int tq = t >> 4;               // q's = {tq, tq+16}

    // ---- phase 1: score ----
    float acc[2][2] = {};
    if (vl > 0) {                        // vl==0 -> pv=1 uniform, skip score
        const float* qpB = eproj + (size_t)(b * QQ + q0) * HH;
        const float* kpB = eproj + (size_t)(BB * QQ + b * KK + k0) * HH;

        for (int hc = 0; hc < HH; hc += 64) {
#pragma unroll
            for (int i = 0; i < 2; ++i) {
                int fi = t + 256 * i; int row = fi >> 4; int c4 = (fi & 15) << 2;
                *(float4*)&qs[row][c4]  = *(const float4*)&qpB[(size_t)row * HH + hc + c4];
                *(float4*)&ks_[row][c4] = *(const float4*)&kpB[(size_t)row * HH + hc + c4];
            }
            __syncthreads();

#pragma unroll 4
            for (int hh = 0; hh < 64; hh += 4) {
                const float4 w4 = *(const float4*)&wv[hc + hh];  // scalar loads
                const float* wa = (const float*)&w4;
                float4 q4[2], k4[2];
                q4[0] = *(float4*)&qs[tq][hh];
                q4[1] = *(float4*)&qs[tq + 16][hh];
                k4[0] = *(float4*)&ks_[tk][hh];
                k4[1] = *(float4*)&ks_[tk + 16][hh];
#pragma unroll
                for (int i = 0; i < 2; ++i) {
                    const float* qa = (const float*)&q4[i];
#pragma unroll
                    for (int j = 0; j < 2; ++j) {
                        const float* ka = (const float*)&k4[j];
#pragma unroll
                        for (int cc = 0; cc < 4; ++cc) {
                            float d = __builtin_fmaf(qa[cc], ka[cc], 1.0f);
                            acc[i][j] += wa[cc] * __builtin_amdgcn_rcpf(d);
                        }
                    }
                }
            }
            __syncthreads();
        }
    }

    // epilogue: masked pv -> pT[k][q] (2-way banks, free); 16-lane row sums
    float sj[2] = {0.f, 0.f};
#pragma unroll
    for (int i = 0; i < 2; ++i)
#pragma unroll
        for (int j = 0; j < 2; ++j) {
            int kg = k0 + tk + 16 * j;
            float pv;
            if (vl == 0) pv = 1.0f;
            else pv = (kg < vl) ? __builtin_amdgcn_exp2f(NEG_TWO_LOG2E * acc[i][j])
                                : 0.0f;
            pT[tk + 16 * j][tq + 16 * i] = pv;
            sj[i] += pv;
        }
#pragma unroll
    for (int off = 1; off < 16; off <<= 1) {
        sj[0] += __shfl_xor(sj[0], off);
        sj[1] += __shfl_xor(sj[1], off);
    }
    if (tk == 0) {
        psum[((size_t)ksb * BB + b) * QQ + q0 + tq]      = sj[0];
        psum[((size_t)ksb * BB + b) * QQ + q0 + tq + 16] = sj[1];
    }
    __syncthreads();

    // ---- phase 2: av ----
    const float* VB = V + ((size_t)b * KK + k0) * DD;
    const int d4 = (t & 63) << 2;        // d base
    const int qh = (t >> 6) << 3;        // q base within tile (0,8,16,24)
    float4 acc4[8] = {};
#pragma unroll 4
    for (int k = 0; k < KCH; ++k) {
        float4 v4 = *(const float4*)&VB[(size_t)k * DD + d4];   // coalesced
        float4 p0 = *(float4*)&pT[k][qh];        // broadcast reads
        float4 p1 = *(float4*)&pT[k][qh + 4];
        acc4[0].x += p0.x * v4.x; acc4[0].y += p0.x * v4.y; acc4[0].z += p0.x * v4.z; acc4[0].w += p0.x * v4.w;
        acc4[1].x += p0.y * v4.x; acc4[1].y += p0.y * v4.y; acc4[1].z += p0.y * v4.z; acc4[1].w += p0.y * v4.w;
        acc4[2].x += p0.z * v4.x; acc4[2].y += p0.z * v4.y; acc4[2].z += p0.z * v4.z; acc4[2].w += p0.z * v4.w;
        acc4[3].x += p0.w * v4.x; acc4[3].y += p0.w * v4.y; acc4[3].z += p0.w * v4.z; acc4[3].w += p0.w * v4.w;
        acc4[4].x += p1.x * v4.x; acc4[4].y += p1.x * v4.y; acc4[4].z += p1.x * v4.z; acc4[4].w += p1.x * v4.w;
        acc4[5].x += p1.y * v4.x; acc4[5].y += p1.y * v4.y; acc4[5].z += p1.y * v4.z; acc4[5].w += p1.y * v4.w;
        acc4[6].x += p1.z * v4.x; acc4[6].y += p1.z * v4.y; acc4[6].z += p1.z * v4.z; acc4[6].w += p1.z * v4.w;
        acc4[7].x += p1.w * v4.x; acc4[7].y += p1.w * v4.y; acc4[7].z += p1.w * v4.z; acc4[7].w += p1.w * v4.w;
    }

#pragma unroll
    for (int qi = 0; qi < 8; ++qi) {
        int q = q0 + qh + qi;
        *(float4*)&partial[(((size_t)ksb * BB + b) * QQ + q) * DD + d4] = acc4[qi];
    }
}

// ---------------------------------------------------------------------------
// K3: mask-aware reduce: sum only the nch(b) live chunks (rest are poison,
// never written), normalize by S. b is uniform per 256-thread block.
// ---------------------------------------------------------------------------
__global__ __launch_bounds__(256) void av_reduce(const float* __restrict__ partial,
                                                 const float* __restrict__ psum,
                                                 const int* __restrict__ vlen,
                                                 float* __restrict__ out) {
    const int i  = blockIdx.x * 256 + threadIdx.x;   // float4 index, 65536 total
    const int bq = i >> 6;                           // b*QQ + q
    const int b  = bq >> 7;
    const int vl = vlen[b];
    const int nch = (vl == 0) ? KSP : ((vl + KCH - 1) / KCH);

    float S = 0.f;
    for (int ks = 0; ks < nch; ++ks) S += psum[(size_t)ks * (BB * QQ) + bq];

    const float4* p4 = (const float4*)partial;
    const int stride4 = BB * QQ * DD / 4;            // 65536
    float4 s = {0.f, 0.f, 0.f, 0.f};
    for (int ks = 0; ks < nch; ++ks) {
        float4 x = p4[(size_t)ks * stride4 + i];
        s.x += x.x; s.y += x.y; s.z += x.z; s.w += x.w;
    }
    const float inv = 1.0f / S;   // S>0 always: p>=8e-12 unmasked, vl==0 -> p=1
    s.x *= inv; s.y *= inv; s.z *= inv; s.w *= inv;
    ((float4*)out)[i] = s;
}

// ---------------------------------------------------------------------------
extern "C" void kernel_launch(void* const* d_in, const int* in_sizes, int n_in,
                              void* d_out, int out_size, void* d_ws, size_t ws_size,
                              hipStream_t stream) {
    const float* queries = (const float*)d_in[0];   // [B,Q,D]
    const float* keys    = (const float*)d_in[1];   // [B,K,D]
    const float* values  = (const float*)d_in[2];   // [B,K,D]
    const float* W_q     = (const float*)d_in[3];   // [H,D]
    const float* W_k     = (const float*)d_in[4];   // [H,D]
    const float* w_v     = (const float*)d_in[5];   // [H]
    const int*   vlen    = (const int*)d_in[6];     // [B]
    float* out = (float*)d_out;

    float* ws      = (float*)d_ws;
    float* eproj   = ws;                                        // 2359296 floats
    float* psum    = eproj + (size_t)(BB * QQ + BB * KK) * HH;  // KSP*B*Q = 32768
    float* partial = psum + (size_t)KSP * BB * QQ;              // KSP*B*Q*D = 33.5 MB
    // no aliasing: scoreav reads eproj while writing partial. ~45 MB of ws.

    // Fused Q+K projection with exp2 epilogue, masked key blocks skipped
    proj_kernel<<<dim3((BB * QQ + BB * KK) / 64, HH / 64, 1), 256, 0, stream>>>(
        queries, keys, W_q, W_k, vlen, eproj);

    // Fused score + A*V, work-compacted over the mask (max 512 dense items)
    scoreav_kernel<<<dim3(KSP * 4 * BB / 2, 1, 1), 256, 0, stream>>>(
        eproj, w_v, vlen, values, partial, psum);

    // Mask-aware reduce + softmax normalization
    av_reduce<<<dim3(BB * QQ * DD / 4 / 256, 1, 1), 256, 0, stream>>>(
        partial, psum, vlen, out);
}